// Round 2
// baseline (1045.922 us; speedup 1.0000x reference)
//
#include <hip/hip_runtime.h>

#define N_NODES   100000
#define N_EDGES   3200000
#define N_GRAPHS  1024
#define HID       64

#define SCAN_B    256
#define NUM_SCAN_BLOCKS ((N_NODES + SCAN_B - 1) / SCAN_B)   // 391

// ---------------- CSR build ----------------

__global__ void k_hist(const int* __restrict__ dst, int* __restrict__ deg) {
    int i = blockIdx.x * blockDim.x + threadIdx.x;
    int stride = gridDim.x * blockDim.x;
    for (; i < N_EDGES; i += stride) atomicAdd(&deg[dst[i]], 1);
}

__global__ void k_scanA(const int* __restrict__ deg, int* __restrict__ rp,
                        int* __restrict__ bsum) {
    __shared__ int s[SCAN_B];
    int i = blockIdx.x * SCAN_B + threadIdx.x;
    int v = (i < N_NODES) ? deg[i] : 0;
    s[threadIdx.x] = v;
    __syncthreads();
    for (int off = 1; off < SCAN_B; off <<= 1) {
        int t = (threadIdx.x >= off) ? s[threadIdx.x - off] : 0;
        __syncthreads();
        s[threadIdx.x] += t;
        __syncthreads();
    }
    int incl = s[threadIdx.x];
    if (i < N_NODES) rp[i] = incl - v;                 // exclusive within block
    if (threadIdx.x == SCAN_B - 1) bsum[blockIdx.x] = incl;
}

__global__ void k_scanB(int* __restrict__ bsum) {
    __shared__ int s[512];
    int v = (threadIdx.x < NUM_SCAN_BLOCKS) ? bsum[threadIdx.x] : 0;
    s[threadIdx.x] = v;
    __syncthreads();
    for (int off = 1; off < 512; off <<= 1) {
        int t = (threadIdx.x >= off) ? s[threadIdx.x - off] : 0;
        __syncthreads();
        s[threadIdx.x] += t;
        __syncthreads();
    }
    if (threadIdx.x < NUM_SCAN_BLOCKS) bsum[threadIdx.x] = s[threadIdx.x] - v; // exclusive
}

__global__ void k_scanC(int* __restrict__ rp, const int* __restrict__ bsum,
                        int* __restrict__ cursor) {
    int i = blockIdx.x * blockDim.x + threadIdx.x;
    if (i < N_NODES) {
        int v = rp[i] + bsum[i / SCAN_B];
        rp[i] = v;
        cursor[i] = v;
    }
    if (i == 0) rp[N_NODES] = N_EDGES;
}

__global__ void k_fill(const int* __restrict__ src, const int* __restrict__ dst,
                       int* __restrict__ cursor, int* __restrict__ srcs) {
    int i = blockIdx.x * blockDim.x + threadIdx.x;
    int stride = gridDim.x * blockDim.x;
    for (; i < N_EDGES; i += stride) {
        int d = dst[i];
        int pos = atomicAdd(&cursor[d], 1);
        srcs[pos] = src[i];
    }
}

// ---------------- Layer 1: agg(x) + MLP1 -> h1 ----------------
// one wave (64 lanes) per node; lane j owns feature j

__global__ void __launch_bounds__(256) k_layer1(
    const float* __restrict__ x, const int* __restrict__ rp,
    const int* __restrict__ srcs,
    const float* __restrict__ W1a, const float* __restrict__ b1a,
    const float* __restrict__ W1b, const float* __restrict__ b1b,
    float* __restrict__ h1) {
    __shared__ float sWb[HID * HID];
    __shared__ float sWa[5 * HID];
    __shared__ float sba[HID], sbb[HID];
    for (int i = threadIdx.x; i < HID * HID; i += 256) sWb[i] = W1b[i];
    for (int i = threadIdx.x; i < 5 * HID; i += 256) sWa[i] = W1a[i];
    if (threadIdx.x < HID) {
        sba[threadIdx.x] = b1a[threadIdx.x];
        sbb[threadIdx.x] = b1b[threadIdx.x];
    }
    __syncthreads();

    int wave = (blockIdx.x * 256 + threadIdx.x) >> 6;
    int lane = threadIdx.x & 63;
    if (wave >= N_NODES) return;
    int n = wave;
    int e0 = rp[n], e1 = rp[n + 1];

    float a0 = 0.f, a1 = 0.f, a2 = 0.f, a3 = 0.f, a4 = 0.f;
    for (int e = e0 + lane; e < e1; e += 64) {
        const float* xs = x + srcs[e] * 5;
        a0 += xs[0]; a1 += xs[1]; a2 += xs[2]; a3 += xs[3]; a4 += xs[4];
    }
#pragma unroll
    for (int m = 1; m < 64; m <<= 1) {
        a0 += __shfl_xor(a0, m, 64);
        a1 += __shfl_xor(a1, m, 64);
        a2 += __shfl_xor(a2, m, 64);
        a3 += __shfl_xor(a3, m, 64);
        a4 += __shfl_xor(a4, m, 64);
    }
    const float* xn = x + n * 5;
    float z0 = xn[0] + a0, z1 = xn[1] + a1, z2 = xn[2] + a2,
          z3 = xn[3] + a3, z4 = xn[4] + a4;

    int j = lane;
    float h = sba[j] + z0 * sWa[0 * HID + j] + z1 * sWa[1 * HID + j] +
              z2 * sWa[2 * HID + j] + z3 * sWa[3 * HID + j] + z4 * sWa[4 * HID + j];
    h = fmaxf(h, 0.f);

    float o = sbb[j];
#pragma unroll
    for (int f = 0; f < HID; ++f) {
        float v = __shfl(h, f, 64);
        o += v * sWb[f * HID + j];
    }
    h1[n * HID + j] = fmaxf(o, 0.f);   // outer relu of layer 1
}

// ---------------- Layer 2: agg(h1) + MLP2 + pooled-sum ----------------

__global__ void __launch_bounds__(256) k_layer2(
    const float* __restrict__ h1, const int* __restrict__ rp,
    const int* __restrict__ srcs, const int* __restrict__ batch,
    const float* __restrict__ W2a, const float* __restrict__ b2a,
    const float* __restrict__ W2b, const float* __restrict__ b2b,
    float* __restrict__ sums, float* __restrict__ cnt) {
    __shared__ float sWa[HID * HID];
    __shared__ float sWb[HID * HID];
    __shared__ float sba[HID], sbb[HID];
    for (int i = threadIdx.x; i < HID * HID; i += 256) {
        sWa[i] = W2a[i];
        sWb[i] = W2b[i];
    }
    if (threadIdx.x < HID) {
        sba[threadIdx.x] = b2a[threadIdx.x];
        sbb[threadIdx.x] = b2b[threadIdx.x];
    }
    __syncthreads();

    int wave = (blockIdx.x * 256 + threadIdx.x) >> 6;
    int lane = threadIdx.x & 63;
    if (wave >= N_NODES) return;
    int n = wave;
    int e0 = rp[n], e1 = rp[n + 1];

    float acc = 0.f;
    int e = e0;
    for (; e + 3 < e1; e += 4) {           // 4-deep for load pipelining
        int sA = srcs[e], sB = srcs[e + 1], sC = srcs[e + 2], sD = srcs[e + 3];
        float vA = h1[sA * HID + lane];
        float vB = h1[sB * HID + lane];
        float vC = h1[sC * HID + lane];
        float vD = h1[sD * HID + lane];
        acc += (vA + vB) + (vC + vD);
    }
    for (; e < e1; ++e) acc += h1[srcs[e] * HID + lane];

    float z = h1[n * HID + lane] + acc;

    int j = lane;
    float t = sba[j];
#pragma unroll
    for (int f = 0; f < HID; ++f) t += __shfl(z, f, 64) * sWa[f * HID + j];
    t = fmaxf(t, 0.f);

    float u = sbb[j];
#pragma unroll
    for (int f = 0; f < HID; ++f) u += __shfl(t, f, 64) * sWb[f * HID + j];
    u = fmaxf(u, 0.f);                      // outer relu of layer 2

    int g = batch[n];
    atomicAdd(&sums[g * HID + j], u);
    if (lane == 0) atomicAdd(&cnt[g], 1.0f);
}

// ---------------- Final: mean pool + classifier ----------------

__global__ void k_final(const float* __restrict__ sums, const float* __restrict__ cnt,
                        const float* __restrict__ Wc, const float* __restrict__ bc,
                        float* __restrict__ out) {
    int g = blockIdx.x;
    int j = threadIdx.x;                    // block of 64
    float c = cnt[g];
    float p = sums[g * HID + j] / fmaxf(c, 1.0f);
    float r0 = p * Wc[j * 2 + 0];
    float r1 = p * Wc[j * 2 + 1];
#pragma unroll
    for (int m = 1; m < 64; m <<= 1) {
        r0 += __shfl_xor(r0, m, 64);
        r1 += __shfl_xor(r1, m, 64);
    }
    if (j == 0) {
        out[g * 2 + 0] = r0 + bc[0];
        out[g * 2 + 1] = r1 + bc[1];
    }
}

// ---------------- launch ----------------

extern "C" void kernel_launch(void* const* d_in, const int* in_sizes, int n_in,
                              void* d_out, int out_size, void* d_ws, size_t ws_size,
                              hipStream_t stream) {
    const float* x   = (const float*)d_in[0];
    const int* ei    = (const int*)d_in[1];
    const int* batch = (const int*)d_in[2];
    const float* W1a = (const float*)d_in[3];
    const float* b1a = (const float*)d_in[4];
    const float* W1b = (const float*)d_in[5];
    const float* b1b = (const float*)d_in[6];
    const float* W2a = (const float*)d_in[7];
    const float* b2a = (const float*)d_in[8];
    const float* W2b = (const float*)d_in[9];
    const float* b2b = (const float*)d_in[10];
    const float* Wc  = (const float*)d_in[11];
    const float* bc  = (const float*)d_in[12];
    float* out = (float*)d_out;

    const int* src = ei;
    const int* dst = ei + N_EDGES;

    // workspace layout (128B aligned chunks)
    char* ws = (char*)d_ws;
    size_t off = 0;
    auto alloc = [&](size_t bytes) {
        char* p = ws + off;
        off += (bytes + 127) & ~size_t(127);
        return p;
    };
    int*   rp     = (int*)alloc((N_NODES + 1) * sizeof(int));
    int*   cursor = (int*)alloc(N_NODES * sizeof(int));       // also deg temp
    int*   bsum   = (int*)alloc(NUM_SCAN_BLOCKS * sizeof(int));
    int*   srcs   = (int*)alloc((size_t)N_EDGES * sizeof(int));
    float* h1     = (float*)alloc((size_t)N_NODES * HID * sizeof(float));
    float* sums   = (float*)alloc((size_t)N_GRAPHS * HID * sizeof(float));
    float* cnt    = (float*)alloc(N_GRAPHS * sizeof(float));

    // zero the accumulators (ws is poisoned 0xAA before every timed launch)
    hipMemsetAsync(cursor, 0, N_NODES * sizeof(int), stream);
    hipMemsetAsync(sums, 0, (size_t)N_GRAPHS * HID * sizeof(float), stream);
    hipMemsetAsync(cnt, 0, N_GRAPHS * sizeof(float), stream);

    // CSR build (cursor holds deg, then write cursors)
    k_hist<<<2048, 256, 0, stream>>>(dst, cursor);
    k_scanA<<<NUM_SCAN_BLOCKS, SCAN_B, 0, stream>>>(cursor, rp, bsum);
    k_scanB<<<1, 512, 0, stream>>>(bsum);
    k_scanC<<<NUM_SCAN_BLOCKS, SCAN_B, 0, stream>>>(rp, bsum, cursor);
    k_fill<<<2048, 256, 0, stream>>>(src, dst, cursor, srcs);

    // layer 1 -> h1
    int node_blocks = (N_NODES * 64 + 255) / 256;   // 1 wave per node
    k_layer1<<<node_blocks, 256, 0, stream>>>(x, rp, srcs, W1a, b1a, W1b, b1b, h1);

    // layer 2 + pooling partial sums
    k_layer2<<<node_blocks, 256, 0, stream>>>(h1, rp, srcs, batch,
                                              W2a, b2a, W2b, b2b, sums, cnt);

    // mean pool + classifier
    k_final<<<N_GRAPHS, 64, 0, stream>>>(sums, cnt, Wc, bc, out);
}

// Round 3
// 956.664 us; speedup vs baseline: 1.0933x; 1.0933x over previous
//
#include <hip/hip_runtime.h>

#define N_NODES   100000
#define N_EDGES   3200000
#define N_GRAPHS  1024
#define HID       64

#define SCAN_B    256
#define NUM_SCAN_BLOCKS ((N_NODES + SCAN_B - 1) / SCAN_B)   // 391

// ---------------- CSR build ----------------

__global__ void k_hist(const int* __restrict__ dst, int* __restrict__ deg) {
    int i = blockIdx.x * blockDim.x + threadIdx.x;
    int stride = gridDim.x * blockDim.x;
    for (; i < N_EDGES; i += stride) atomicAdd(&deg[dst[i]], 1);
}

__global__ void k_scanA(const int* __restrict__ deg, int* __restrict__ rp,
                        int* __restrict__ bsum) {
    __shared__ int s[SCAN_B];
    int i = blockIdx.x * SCAN_B + threadIdx.x;
    int v = (i < N_NODES) ? deg[i] : 0;
    s[threadIdx.x] = v;
    __syncthreads();
    for (int off = 1; off < SCAN_B; off <<= 1) {
        int t = (threadIdx.x >= off) ? s[threadIdx.x - off] : 0;
        __syncthreads();
        s[threadIdx.x] += t;
        __syncthreads();
    }
    int incl = s[threadIdx.x];
    if (i < N_NODES) rp[i] = incl - v;                 // exclusive within block
    if (threadIdx.x == SCAN_B - 1) bsum[blockIdx.x] = incl;
}

__global__ void k_scanB(int* __restrict__ bsum) {
    __shared__ int s[512];
    int v = (threadIdx.x < NUM_SCAN_BLOCKS) ? bsum[threadIdx.x] : 0;
    s[threadIdx.x] = v;
    __syncthreads();
    for (int off = 1; off < 512; off <<= 1) {
        int t = (threadIdx.x >= off) ? s[threadIdx.x - off] : 0;
        __syncthreads();
        s[threadIdx.x] += t;
        __syncthreads();
    }
    if (threadIdx.x < NUM_SCAN_BLOCKS) bsum[threadIdx.x] = s[threadIdx.x] - v; // exclusive
}

__global__ void k_scanC(int* __restrict__ rp, const int* __restrict__ bsum,
                        int* __restrict__ cursor) {
    int i = blockIdx.x * blockDim.x + threadIdx.x;
    if (i < N_NODES) {
        int v = rp[i] + bsum[i / SCAN_B];
        rp[i] = v;
        cursor[i] = v;
    }
    if (i == 0) rp[N_NODES] = N_EDGES;
}

__global__ void k_fill(const int* __restrict__ src, const int* __restrict__ dst,
                       int* __restrict__ cursor, int* __restrict__ srcs) {
    int i = blockIdx.x * blockDim.x + threadIdx.x;
    int stride = gridDim.x * blockDim.x;
    for (; i < N_EDGES; i += stride) {
        int d = dst[i];
        int pos = atomicAdd(&cursor[d], 1);
        srcs[pos] = src[i];
    }
}

// ---------------- Layer 1: agg(x) + MLP1 -> h1 ----------------
// one wave (64 lanes) per node; lane j owns feature j
// 512-thread blocks: LDS 17.8KB -> 4 blocks/CU (thread-capped) = 100% occ.

__global__ void __launch_bounds__(512) k_layer1(
    const float* __restrict__ x, const int* __restrict__ rp,
    const int* __restrict__ srcs,
    const float* __restrict__ W1a, const float* __restrict__ b1a,
    const float* __restrict__ W1b, const float* __restrict__ b1b,
    float* __restrict__ h1) {
    __shared__ float sWb[HID * HID];
    __shared__ float sWa[5 * HID];
    __shared__ float sba[HID], sbb[HID];
    for (int i = threadIdx.x; i < HID * HID; i += 512) sWb[i] = W1b[i];
    for (int i = threadIdx.x; i < 5 * HID; i += 512) sWa[i] = W1a[i];
    if (threadIdx.x < HID) {
        sba[threadIdx.x] = b1a[threadIdx.x];
        sbb[threadIdx.x] = b1b[threadIdx.x];
    }
    __syncthreads();

    int wave = (blockIdx.x * 512 + threadIdx.x) >> 6;
    int lane = threadIdx.x & 63;
    if (wave >= N_NODES) return;
    int n = wave;
    int e0 = rp[n], e1 = rp[n + 1];

    float a0 = 0.f, a1 = 0.f, a2 = 0.f, a3 = 0.f, a4 = 0.f;
    for (int e = e0 + lane; e < e1; e += 64) {
        const float* xs = x + srcs[e] * 5;
        a0 += xs[0]; a1 += xs[1]; a2 += xs[2]; a3 += xs[3]; a4 += xs[4];
    }
#pragma unroll
    for (int m = 1; m < 64; m <<= 1) {
        a0 += __shfl_xor(a0, m, 64);
        a1 += __shfl_xor(a1, m, 64);
        a2 += __shfl_xor(a2, m, 64);
        a3 += __shfl_xor(a3, m, 64);
        a4 += __shfl_xor(a4, m, 64);
    }
    const float* xn = x + n * 5;
    float z0 = xn[0] + a0, z1 = xn[1] + a1, z2 = xn[2] + a2,
          z3 = xn[3] + a3, z4 = xn[4] + a4;

    int j = lane;
    float h = sba[j] + z0 * sWa[0 * HID + j] + z1 * sWa[1 * HID + j] +
              z2 * sWa[2 * HID + j] + z3 * sWa[3 * HID + j] + z4 * sWa[4 * HID + j];
    h = fmaxf(h, 0.f);

    float o = sbb[j];
#pragma unroll
    for (int f = 0; f < HID; ++f) {
        float v = __shfl(h, f, 64);
        o += v * sWb[f * HID + j];
    }
    h1[n * HID + j] = fmaxf(o, 0.f);   // outer relu of layer 1
}

// ---------------- Layer 2: agg(h1) + MLP2 + pooled-sum ----------------
// quad-gather: wave = 4 groups x 16 lanes; group q loads edge-row (e0+q, +4, ...)
// as float4 (16 lanes x 16B = 256B coalesced). 512-thr blocks -> 100% occupancy.

__global__ void __launch_bounds__(512) k_layer2(
    const float* __restrict__ h1, const int* __restrict__ rp,
    const int* __restrict__ srcs, const int* __restrict__ batch,
    const float* __restrict__ W2a, const float* __restrict__ b2a,
    const float* __restrict__ W2b, const float* __restrict__ b2b,
    float* __restrict__ sums, float* __restrict__ cnt) {
    __shared__ float sWa[HID * HID];
    __shared__ float sWb[HID * HID];
    __shared__ float sba[HID], sbb[HID];
    for (int i = threadIdx.x; i < HID * HID; i += 512) {
        sWa[i] = W2a[i];
        sWb[i] = W2b[i];
    }
    if (threadIdx.x < HID) {
        sba[threadIdx.x] = b2a[threadIdx.x];
        sbb[threadIdx.x] = b2b[threadIdx.x];
    }
    __syncthreads();

    int wave = (blockIdx.x * 512 + threadIdx.x) >> 6;
    int lane = threadIdx.x & 63;
    if (wave >= N_NODES) return;
    int n = wave;
    int q = lane >> 4;          // edge slot within group-of-4
    int c = lane & 15;          // feature quad
    int e0 = rp[n], e1 = rp[n + 1];

    float ax = 0.f, ay = 0.f, az = 0.f, aw = 0.f;
#pragma unroll 2
    for (int e = e0 + q; e < e1; e += 4) {
        int s = srcs[e];
        const float4 v = *reinterpret_cast<const float4*>(h1 + (size_t)s * HID + c * 4);
        ax += v.x; ay += v.y; az += v.z; aw += v.w;
    }
    // reduce the 4 edge-slot groups
#pragma unroll
    for (int m = 16; m < 64; m <<= 1) {
        ax += __shfl_xor(ax, m, 64);
        ay += __shfl_xor(ay, m, 64);
        az += __shfl_xor(az, m, 64);
        aw += __shfl_xor(aw, m, 64);
    }
    const float4 self = *reinterpret_cast<const float4*>(h1 + (size_t)n * HID + c * 4);
    // z replicated across the 4 groups; lane fq (0..15) holds features 4fq..4fq+3
    float zx = ax + self.x, zy = ay + self.y, zz = az + self.z, zw = aw + self.w;

    int j = lane;
    float t = sba[j];
#pragma unroll
    for (int fq = 0; fq < 16; ++fq) {
        float vx = __shfl(zx, fq, 64);
        float vy = __shfl(zy, fq, 64);
        float vz = __shfl(zz, fq, 64);
        float vw = __shfl(zw, fq, 64);
        t += vx * sWa[(fq * 4 + 0) * HID + j];
        t += vy * sWa[(fq * 4 + 1) * HID + j];
        t += vz * sWa[(fq * 4 + 2) * HID + j];
        t += vw * sWa[(fq * 4 + 3) * HID + j];
    }
    t = fmaxf(t, 0.f);

    float u = sbb[j];
#pragma unroll
    for (int f = 0; f < HID; ++f) u += __shfl(t, f, 64) * sWb[f * HID + j];
    u = fmaxf(u, 0.f);                      // outer relu of layer 2

    int g = batch[n];
    atomicAdd(&sums[g * HID + j], u);
    if (lane == 0) atomicAdd(&cnt[g], 1.0f);
}

// ---------------- Final: mean pool + classifier ----------------

__global__ void k_final(const float* __restrict__ sums, const float* __restrict__ cnt,
                        const float* __restrict__ Wc, const float* __restrict__ bc,
                        float* __restrict__ out) {
    int g = blockIdx.x;
    int j = threadIdx.x;                    // block of 64
    float c = cnt[g];
    float p = sums[g * HID + j] / fmaxf(c, 1.0f);
    float r0 = p * Wc[j * 2 + 0];
    float r1 = p * Wc[j * 2 + 1];
#pragma unroll
    for (int m = 1; m < 64; m <<= 1) {
        r0 += __shfl_xor(r0, m, 64);
        r1 += __shfl_xor(r1, m, 64);
    }
    if (j == 0) {
        out[g * 2 + 0] = r0 + bc[0];
        out[g * 2 + 1] = r1 + bc[1];
    }
}

// ---------------- launch ----------------

extern "C" void kernel_launch(void* const* d_in, const int* in_sizes, int n_in,
                              void* d_out, int out_size, void* d_ws, size_t ws_size,
                              hipStream_t stream) {
    const float* x   = (const float*)d_in[0];
    const int* ei    = (const int*)d_in[1];
    const int* batch = (const int*)d_in[2];
    const float* W1a = (const float*)d_in[3];
    const float* b1a = (const float*)d_in[4];
    const float* W1b = (const float*)d_in[5];
    const float* b1b = (const float*)d_in[6];
    const float* W2a = (const float*)d_in[7];
    const float* b2a = (const float*)d_in[8];
    const float* W2b = (const float*)d_in[9];
    const float* b2b = (const float*)d_in[10];
    const float* Wc  = (const float*)d_in[11];
    const float* bc  = (const float*)d_in[12];
    float* out = (float*)d_out;

    const int* src = ei;
    const int* dst = ei + N_EDGES;

    // workspace layout (128B aligned chunks)
    char* ws = (char*)d_ws;
    size_t off = 0;
    auto alloc = [&](size_t bytes) {
        char* p = ws + off;
        off += (bytes + 127) & ~size_t(127);
        return p;
    };
    int*   rp     = (int*)alloc((N_NODES + 1) * sizeof(int));
    int*   cursor = (int*)alloc(N_NODES * sizeof(int));       // also deg temp
    int*   bsum   = (int*)alloc(NUM_SCAN_BLOCKS * sizeof(int));
    int*   srcs   = (int*)alloc((size_t)N_EDGES * sizeof(int));
    float* h1     = (float*)alloc((size_t)N_NODES * HID * sizeof(float));
    float* sums   = (float*)alloc((size_t)(N_GRAPHS * HID + N_GRAPHS) * sizeof(float));
    float* cnt    = sums + (size_t)N_GRAPHS * HID;

    // zero the accumulators (ws is poisoned 0xAA before every timed launch)
    hipMemsetAsync(cursor, 0, N_NODES * sizeof(int), stream);
    hipMemsetAsync(sums, 0, (size_t)(N_GRAPHS * HID + N_GRAPHS) * sizeof(float), stream);

    // CSR build (cursor holds deg, then write cursors)
    k_hist<<<2048, 256, 0, stream>>>(dst, cursor);
    k_scanA<<<NUM_SCAN_BLOCKS, SCAN_B, 0, stream>>>(cursor, rp, bsum);
    k_scanB<<<1, 512, 0, stream>>>(bsum);
    k_scanC<<<NUM_SCAN_BLOCKS, SCAN_B, 0, stream>>>(rp, bsum, cursor);
    k_fill<<<2048, 256, 0, stream>>>(src, dst, cursor, srcs);

    // layer 1 -> h1 (8 waves / 512-thread block, 1 wave per node)
    int blocks8 = (N_NODES + 7) / 8;
    k_layer1<<<blocks8, 512, 0, stream>>>(x, rp, srcs, W1a, b1a, W1b, b1b, h1);

    // layer 2 + pooling partial sums
    k_layer2<<<blocks8, 512, 0, stream>>>(h1, rp, srcs, batch,
                                          W2a, b2a, W2b, b2b, sums, cnt);

    // mean pool + classifier
    k_final<<<N_GRAPHS, 64, 0, stream>>>(sums, cnt, Wc, bc, out);
}